// Round 11
// baseline (318.552 us; speedup 1.0000x reference)
//
#include <hip/hip_runtime.h>
#include <hip/hip_bf16.h>
#include <float.h>

#define DIM 32
#define KCODES 1024
#define NROWS 262144

// output offsets (floats, reference return order)
#define O_ZQ   0
#define O_CB   8388608
#define O_CL   8388609
#define O_IDX  8388610
#define O_UN   8650754
#define O_EMB  8650755
#define O_CS   8683523
#define O_EA   8684547

// workspace layout (float offsets)
#define W_PCNT 0          // counts[1024] via global atomics (memset each call)
#define W_ESUM 1024       // embed_sum[32768] via global atomics (memset each call)
#define W_PCOM 33792      // [256] commitment partials (scatter blocks)
#define W_NORM 34048      // [1024]
#define W_ZZH  35072      // [262144] zz/2
#define W_EEH  297216     // [1024] ee/2
#define W_BF   298240     // ushort region: 64 kt x 3 splits x 64 lanes x 8 bf16 (192KB)

typedef __attribute__((ext_vector_type(8))) short bf16x8;
typedef __attribute__((ext_vector_type(4))) float f32x4;

#define MFMA16 __builtin_amdgcn_mfma_f32_16x16x32_bf16

static __device__ __forceinline__ unsigned short f2bf(float x) {
    __hip_bfloat16 h = __float2bfloat16(x);           // RNE
    return __builtin_bit_cast(unsigned short, h);
}
static __device__ __forceinline__ float bf2f(unsigned short u) {
    unsigned int v = ((unsigned int)u) << 16;
    return __builtin_bit_cast(float, v);
}
static __device__ __forceinline__ float pw8_sq(const float* x) {
    float w[32];
    #pragma unroll
    for (int i = 0; i < 32; ++i) w[i] = __fmul_rn(x[i], x[i]);
    float r[8];
    #pragma unroll
    for (int j = 0; j < 8; ++j) r[j] = ((w[j] + w[8 + j]) + w[16 + j]) + w[24 + j];
    return ((r[0] + r[1]) + (r[2] + r[3])) + ((r[4] + r[5]) + (r[6] + r[7]));
}

// ---------------- P1: zz/2 per row ----------------
__global__ __launch_bounds__(256) void vq_prep_z(
    const float* __restrict__ z, float* __restrict__ ws)
{
    int row = blockIdx.x * 256 + threadIdx.x;
    float x[32];
    const float4* zg = (const float4*)(z + (size_t)row * DIM);
    #pragma unroll
    for (int q = 0; q < 8; ++q) {
        float4 v = zg[q];
        x[4*q] = v.x; x[4*q+1] = v.y; x[4*q+2] = v.z; x[4*q+3] = v.w;
    }
    ws[W_ZZH + row] = 0.5f * pw8_sq(x);
}

// ---------------- P2: ee/2 + codebook bf16x3 fragments ----------------
__global__ __launch_bounds__(256) void vq_prep_e(
    const float* __restrict__ emb, float* __restrict__ ws)
{
    int c = blockIdx.x * 256 + threadIdx.x;
    float x[32];
    const float4* eg = (const float4*)(emb + (size_t)c * DIM);
    #pragma unroll
    for (int q = 0; q < 8; ++q) {
        float4 v = eg[q];
        x[4*q] = v.x; x[4*q+1] = v.y; x[4*q+2] = v.z; x[4*q+3] = v.w;
    }
    ws[W_EEH + c] = 0.5f * pw8_sq(x);

    unsigned short hb[3][32];
    #pragma unroll
    for (int i = 0; i < 32; ++i) {
        float v = x[i];
        unsigned short h0 = f2bf(v); float f0 = bf2f(h0); float r1 = v - f0;
        unsigned short h1 = f2bf(r1); float f1 = bf2f(h1); float r2 = r1 - f1;
        unsigned short h2 = f2bf(r2);   // exact: v = h0+h1+h2
        hb[0][i] = h0; hb[1][i] = h1; hb[2][i] = h2;
    }
    // B-frag: lane l holds B[k=(l>>4)*8+e][col=l&15]; frag index (kt*3+s)*64+lane
    bf16x8* bf = (bf16x8*)(ws + W_BF);
    int kt = c >> 4, cl = c & 15;
    #pragma unroll
    for (int s = 0; s < 3; ++s) {
        #pragma unroll
        for (int j = 0; j < 4; ++j) {
            bf16x8 pk;
            #pragma unroll
            for (int e = 0; e < 8; ++e) pk[e] = (short)hb[s][j*8 + e];
            bf[(kt*3 + s)*64 + j*16 + cl] = pk;
        }
    }
}

// ---------------- A: MFMA distance argmin -> indices (R5/K100 structure) ----
// 1024 blocks x 256 threads (4 waves), j=4 row-tiles/wave, B-frags stream
// from L2 (no LDS staging, no k-loop barriers). Distance epilogue = R2-exact
// FP sequence. Only change vs the 100.6us-measured kernel: kt unroll 2 -> 4.
__global__ __launch_bounds__(256, 4) void vq_argmin_mfma(
    const float* __restrict__ z, const float* __restrict__ wsc,
    float* __restrict__ out)
{
    __shared__ float eesh[1024];
    const int t = threadIdx.x;
    const int lane = t & 63, w = t >> 6;
    const int g = lane >> 4, lr = lane & 15;

    const bf16x8* bvG = (const bf16x8*)(wsc + W_BF);

    #pragma unroll
    for (int i = 0; i < 4; ++i) eesh[t + i * 256] = wsc[W_EEH + t + i * 256];

    // ---- load 4 z row-tiles: split to bf16x3 A-frags + zz ----
    const int rtbase = blockIdx.x * 16 + w * 4;
    bf16x8 zh[4], zm[4], zl[4];
    float zza[4][4];
    #pragma unroll
    for (int j = 0; j < 4; ++j) {
        const int rtg = rtbase + j;
        const float* zp = z + ((size_t)(rtg * 16 + lr)) * DIM + g * 8;
        float4 a4 = *(const float4*)zp, b4 = *(const float4*)(zp + 4);
        float xs[8] = {a4.x, a4.y, a4.z, a4.w, b4.x, b4.y, b4.z, b4.w};
        #pragma unroll
        for (int e = 0; e < 8; ++e) {
            float v = xs[e];
            unsigned short h0 = f2bf(v); float f0 = bf2f(h0); float r1 = v - f0;
            unsigned short h1 = f2bf(r1); float f1 = bf2f(h1); float r2 = r1 - f1;
            zh[j][e] = (short)h0; zm[j][e] = (short)h1; zl[j][e] = (short)f2bf(r2);
        }
        float4 zv = *(const float4*)(wsc + W_ZZH + rtg * 16 + g * 4);
        zza[j][0] = zv.x; zza[j][1] = zv.y; zza[j][2] = zv.z; zza[j][3] = zv.w;
    }

    unsigned int Bb[4][4]; int Kk[4][4];
    #pragma unroll
    for (int j = 0; j < 4; ++j)
        #pragma unroll
        for (int r = 0; r < 4; ++r) { Bb[j][r] = 0xFFFFFFFFu; Kk[j][r] = 0; }

    __syncthreads();   // eesh ready

    #pragma unroll 4
    for (int kt = 0; kt < 64; ++kt) {
        bf16x8 eh = bvG[(kt * 3 + 0) * 64 + lane];
        bf16x8 em = bvG[(kt * 3 + 1) * 64 + lane];
        bf16x8 el = bvG[(kt * 3 + 2) * 64 + lane];
        float ee_l = eesh[kt * 16 + lr];
        int kge = kt * 16 + lr;
        #pragma unroll
        for (int j = 0; j < 4; ++j) {
            f32x4 a = {0.f, 0.f, 0.f, 0.f};
            a = MFMA16(zh[j], eh, a, 0, 0, 0);
            a = MFMA16(zh[j], em, a, 0, 0, 0);
            a = MFMA16(zm[j], eh, a, 0, 0, 0);
            a = MFMA16(zh[j], el, a, 0, 0, 0);
            a = MFMA16(zl[j], eh, a, 0, 0, 0);
            a = MFMA16(zm[j], em, a, 0, 0, 0);
            #pragma unroll
            for (int r = 0; r < 4; ++r) {
                float v = (zza[j][r] + ee_l) - a[r];     // = d/2 (R2-exact order)
                unsigned int u = __builtin_bit_cast(unsigned int, v);
                bool tk = u < Bb[j][r];
                Bb[j][r] = tk ? u : Bb[j][r];
                Kk[j][r] = tk ? kge : Kk[j][r];
            }
        }
    }

    // ---- cross-lane reduce within 16-lane col groups, tie -> lowest k ----
    #pragma unroll
    for (int j = 0; j < 4; ++j) {
        const int rtg = rtbase + j;
        #pragma unroll
        for (int r = 0; r < 4; ++r) {
            unsigned int b0 = Bb[j][r]; int k0 = Kk[j][r];
            #pragma unroll
            for (int m = 1; m < 16; m <<= 1) {
                unsigned int ob = __shfl_xor((int)b0, m, 16); int ok = __shfl_xor(k0, m, 16);
                bool tk = (ob < b0) || (ob == b0 && ok < k0);
                b0 = tk ? ob : b0; k0 = tk ? ok : k0;
            }
            if (lr == 0) out[O_IDX + rtg * 16 + g * 4 + r] = (float)k0;
        }
    }
}

// ---------------- S: gather z_q + commitment + hist + atomic embed_sum ------
__global__ __launch_bounds__(1024) void vq_scatter(
    const float* __restrict__ z, const float* __restrict__ emb,
    float* __restrict__ out, float* __restrict__ ws)
{
    __shared__ float smem[34816];   // [1024][33] sums + counts at 33792
    __shared__ float red[16];
    const int t = threadIdx.x;
    const int b = blockIdx.x;
    {
        float4 zero4 = {0.f, 0.f, 0.f, 0.f};
        float4* s4 = (float4*)smem;
        #pragma unroll
        for (int i = 0; i < 9; ++i) { int j = t + i * 1024; if (j < 8704) s4[j] = zero4; }
    }
    __syncthreads();

    const int row = b * 1024 + t;
    const int kk = (int)out[O_IDX + row];
    const float4* zg = (const float4*)(z + (size_t)row * DIM);
    const float4* eg = (const float4*)(emb + (size_t)kk * DIM);
    float4* og = (float4*)(out + O_ZQ + (size_t)row * DIM);
    float zv[32];
    float csum = 0.f;
    #pragma unroll
    for (int q = 0; q < 8; ++q) {
        float4 v = zg[q];
        float4 e = eg[q];
        zv[4*q] = v.x; zv[4*q+1] = v.y; zv[4*q+2] = v.z; zv[4*q+3] = v.w;
        float d0 = v.x - e.x, d1 = v.y - e.y, d2 = v.z - e.z, d3 = v.w - e.w;
        csum = fmaf(d0, d0, csum); csum = fmaf(d1, d1, csum);
        csum = fmaf(d2, d2, csum); csum = fmaf(d3, d3, csum);
        float4 o;
        o.x = v.x + (e.x - v.x); o.y = v.y + (e.y - v.y);
        o.z = v.z + (e.z - v.z); o.w = v.w + (e.w - v.w);
        og[q] = o;
    }
    atomicAdd(&smem[33792 + kk], 1.0f);
    #pragma unroll
    for (int i = 0; i < 32; ++i) atomicAdd(&smem[kk * 33 + i], zv[i]);

    #pragma unroll
    for (int off = 32; off > 0; off >>= 1) csum += __shfl_down(csum, off, 64);
    if ((t & 63) == 0) red[t >> 6] = csum;
    __syncthreads();

    // counts: global atomic adds of integer-valued floats (exact, deterministic)
    float cpart = smem[33792 + t];
    if (cpart != 0.f) atomicAdd(&ws[W_PCNT + t], cpart);

    // embed_sum: skip-zero coalesced global atomic accumulation (no PSUM panels)
    #pragma unroll
    for (int c = 0; c < 32; ++c) {
        int idx = t + c * 1024;              // linear over 32768
        int code = idx >> 5, elem = idx & 31;
        if (smem[33792 + code] != 0.f)
            atomicAdd(&ws[W_ESUM + idx], smem[code * 33 + elem]);
    }
    if (t == 0) {
        float s = 0.f;
        #pragma unroll
        for (int i = 0; i < 16; ++i) s += red[i];
        ws[W_PCOM + b] = s;
    }
}

__global__ __launch_bounds__(1024) void vq_epilogue0(
    const float* __restrict__ cs_in, const float* __restrict__ ws,
    float* __restrict__ out, float* __restrict__ wsw)
{
    __shared__ float s1[1024], s2[1024];
    const int k = threadIdx.x;
    float c = ws[W_PCNT + k];
    float csn = 0.99f * cs_in[k] + 0.01f * c;
    out[O_CS + k] = csn;
    s1[k] = csn;
    s2[k] = (c == 0.f) ? 1.f : 0.f;
    __syncthreads();
    for (int s = 512; s > 0; s >>= 1) {
        if (k < s) { s1[k] += s1[k + s]; s2[k] += s2[k + s]; }
        __syncthreads();
    }
    float n = s1[0];
    float unused = s2[0];
    wsw[W_NORM + k] = n * (csn + 1e-5f) / (n + 1024.f * 1e-5f);
    __syncthreads();
    s1[k] = (k < 256) ? ws[W_PCOM + k] : 0.f;
    __syncthreads();
    for (int s = 512; s > 0; s >>= 1) {
        if (k < s) s1[k] += s1[k + s];
        __syncthreads();
    }
    if (k == 0) {
        out[O_CB] = 0.f;
        out[O_CL] = s1[0] / 8388608.f;
        out[O_UN] = unused;
    }
}

__global__ void vq_epilogue1(
    const float* __restrict__ ea, const float* __restrict__ ws,
    float* __restrict__ out)
{
    const int id = blockIdx.x * 128 + threadIdx.x;   // < 32768
    float es = ws[W_ESUM + id];
    float ean = 0.99f * ea[id] + 0.01f * es;
    out[O_EA + id] = ean;
    out[O_EMB + id] = ean / ws[W_NORM + (id >> 5)];
}

extern "C" void kernel_launch(void* const* d_in, const int* in_sizes, int n_in,
                              void* d_out, int out_size, void* d_ws, size_t ws_size,
                              hipStream_t stream)
{
    const float* z   = (const float*)d_in[0];
    const float* emb = (const float*)d_in[1];
    const float* ea  = (const float*)d_in[2];
    const float* cs  = (const float*)d_in[3];
    float* out = (float*)d_out;
    float* ws  = (float*)d_ws;

    // zero counts + embed_sum accumulators (contiguous: 33792 floats)
    hipMemsetAsync(ws + W_PCNT, 0, (KCODES + KCODES * DIM) * sizeof(float), stream);
    vq_prep_z<<<1024, 256, 0, stream>>>(z, ws);
    vq_prep_e<<<4, 256, 0, stream>>>(emb, ws);
    vq_argmin_mfma<<<1024, 256, 0, stream>>>(z, ws, out);
    vq_scatter<<<256, 1024, 0, stream>>>(z, emb, out, ws);
    vq_epilogue0<<<1, 1024, 0, stream>>>(cs, ws, out, ws);
    vq_epilogue1<<<256, 128, 0, stream>>>(ea, ws, out);
}

// Round 12
// 173.842 us; speedup vs baseline: 1.8324x; 1.8324x over previous
//
#include <hip/hip_runtime.h>
#include <hip/hip_bf16.h>
#include <float.h>

#define DIM 32
#define KCODES 1024
#define NROWS 262144

// output offsets (floats, reference return order)
#define O_ZQ   0
#define O_CB   8388608
#define O_CL   8388609
#define O_IDX  8388610
#define O_UN   8650754
#define O_EMB  8650755
#define O_CS   8683523
#define O_EA   8684547

// workspace layout (float offsets) — R6-round proven layout
#define W_PCNT 0          // counts[1024] via global atomics (memset each call)
#define W_PSUM 262144     // [256][1024*32] scatter partials (32MB)
#define W_PCOM 8650752    // [256] commitment partials (scatter blocks)
#define W_NORM 8651008    // [1024]
#define W_ZZH  8652032    // [262144] zz/2
#define W_EEH  8914176    // [1024] ee/2
#define W_BF   8915200    // ushort region: 64 kt x 3 splits x 64 lanes x 8 bf16 (192KB)

typedef __attribute__((ext_vector_type(8))) short bf16x8;
typedef __attribute__((ext_vector_type(4))) float f32x4;

#define MFMA16 __builtin_amdgcn_mfma_f32_16x16x32_bf16

static __device__ __forceinline__ unsigned short f2bf(float x) {
    __hip_bfloat16 h = __float2bfloat16(x);           // RNE
    return __builtin_bit_cast(unsigned short, h);
}
static __device__ __forceinline__ float bf2f(unsigned short u) {
    unsigned int v = ((unsigned int)u) << 16;
    return __builtin_bit_cast(float, v);
}
static __device__ __forceinline__ float pw8_sq(const float* x) {
    float w[32];
    #pragma unroll
    for (int i = 0; i < 32; ++i) w[i] = __fmul_rn(x[i], x[i]);
    float r[8];
    #pragma unroll
    for (int j = 0; j < 8; ++j) r[j] = ((w[j] + w[8 + j]) + w[16 + j]) + w[24 + j];
    return ((r[0] + r[1]) + (r[2] + r[3])) + ((r[4] + r[5]) + (r[6] + r[7]));
}

// ---------------- P1: zz/2 per row ----------------
__global__ __launch_bounds__(256) void vq_prep_z(
    const float* __restrict__ z, float* __restrict__ ws)
{
    int row = blockIdx.x * 256 + threadIdx.x;
    float x[32];
    const float4* zg = (const float4*)(z + (size_t)row * DIM);
    #pragma unroll
    for (int q = 0; q < 8; ++q) {
        float4 v = zg[q];
        x[4*q] = v.x; x[4*q+1] = v.y; x[4*q+2] = v.z; x[4*q+3] = v.w;
    }
    ws[W_ZZH + row] = 0.5f * pw8_sq(x);
}

// ---------------- P2: ee/2 + codebook bf16x3 fragments ----------------
__global__ __launch_bounds__(256) void vq_prep_e(
    const float* __restrict__ emb, float* __restrict__ ws)
{
    int c = blockIdx.x * 256 + threadIdx.x;
    float x[32];
    const float4* eg = (const float4*)(emb + (size_t)c * DIM);
    #pragma unroll
    for (int q = 0; q < 8; ++q) {
        float4 v = eg[q];
        x[4*q] = v.x; x[4*q+1] = v.y; x[4*q+2] = v.z; x[4*q+3] = v.w;
    }
    ws[W_EEH + c] = 0.5f * pw8_sq(x);

    unsigned short hb[3][32];
    #pragma unroll
    for (int i = 0; i < 32; ++i) {
        float v = x[i];
        unsigned short h0 = f2bf(v); float f0 = bf2f(h0); float r1 = v - f0;
        unsigned short h1 = f2bf(r1); float f1 = bf2f(h1); float r2 = r1 - f1;
        unsigned short h2 = f2bf(r2);   // exact: v = h0+h1+h2
        hb[0][i] = h0; hb[1][i] = h1; hb[2][i] = h2;
    }
    // B-frag: lane l holds B[k=(l>>4)*8+e][col=l&15]; frag index (kt*3+s)*64+lane
    bf16x8* bf = (bf16x8*)(ws + W_BF);
    int kt = c >> 4, cl = c & 15;
    #pragma unroll
    for (int s = 0; s < 3; ++s) {
        #pragma unroll
        for (int j = 0; j < 4; ++j) {
            bf16x8 pk;
            #pragma unroll
            for (int e = 0; e < 8; ++e) pk[e] = (short)hb[s][j*8 + e];
            bf[(kt*3 + s)*64 + j*16 + cl] = pk;
        }
    }
}

// ---------------- A: MFMA distance argmin -> indices (R5 proven, 100.6us) ---
// 1024 blocks x 256 threads (4 waves), j=4 row-tiles/wave, B-frags stream
// from L2 (no LDS staging, no k-loop barriers). kt unroll 2 — do NOT deepen:
// unroll 4 forces z-load rematerialization in the hot loop (581MB HBM, R10).
__global__ __launch_bounds__(256, 4) void vq_argmin_mfma(
    const float* __restrict__ z, const float* __restrict__ wsc,
    float* __restrict__ out)
{
    __shared__ float eesh[1024];
    const int t = threadIdx.x;
    const int lane = t & 63, w = t >> 6;
    const int g = lane >> 4, lr = lane & 15;

    const bf16x8* bvG = (const bf16x8*)(wsc + W_BF);

    #pragma unroll
    for (int i = 0; i < 4; ++i) eesh[t + i * 256] = wsc[W_EEH + t + i * 256];

    // ---- load 4 z row-tiles: split to bf16x3 A-frags + zz ----
    const int rtbase = blockIdx.x * 16 + w * 4;
    bf16x8 zh[4], zm[4], zl[4];
    float zza[4][4];
    #pragma unroll
    for (int j = 0; j < 4; ++j) {
        const int rtg = rtbase + j;
        const float* zp = z + ((size_t)(rtg * 16 + lr)) * DIM + g * 8;
        float4 a4 = *(const float4*)zp, b4 = *(const float4*)(zp + 4);
        float xs[8] = {a4.x, a4.y, a4.z, a4.w, b4.x, b4.y, b4.z, b4.w};
        #pragma unroll
        for (int e = 0; e < 8; ++e) {
            float v = xs[e];
            unsigned short h0 = f2bf(v); float f0 = bf2f(h0); float r1 = v - f0;
            unsigned short h1 = f2bf(r1); float f1 = bf2f(h1); float r2 = r1 - f1;
            zh[j][e] = (short)h0; zm[j][e] = (short)h1; zl[j][e] = (short)f2bf(r2);
        }
        float4 zv = *(const float4*)(wsc + W_ZZH + rtg * 16 + g * 4);
        zza[j][0] = zv.x; zza[j][1] = zv.y; zza[j][2] = zv.z; zza[j][3] = zv.w;
    }

    unsigned int Bb[4][4]; int Kk[4][4];
    #pragma unroll
    for (int j = 0; j < 4; ++j)
        #pragma unroll
        for (int r = 0; r < 4; ++r) { Bb[j][r] = 0xFFFFFFFFu; Kk[j][r] = 0; }

    __syncthreads();   // eesh ready

    #pragma unroll 2
    for (int kt = 0; kt < 64; ++kt) {
        bf16x8 eh = bvG[(kt * 3 + 0) * 64 + lane];
        bf16x8 em = bvG[(kt * 3 + 1) * 64 + lane];
        bf16x8 el = bvG[(kt * 3 + 2) * 64 + lane];
        float ee_l = eesh[kt * 16 + lr];
        int kge = kt * 16 + lr;
        #pragma unroll
        for (int j = 0; j < 4; ++j) {
            f32x4 a = {0.f, 0.f, 0.f, 0.f};
            a = MFMA16(zh[j], eh, a, 0, 0, 0);
            a = MFMA16(zh[j], em, a, 0, 0, 0);
            a = MFMA16(zm[j], eh, a, 0, 0, 0);
            a = MFMA16(zh[j], el, a, 0, 0, 0);
            a = MFMA16(zl[j], eh, a, 0, 0, 0);
            a = MFMA16(zm[j], em, a, 0, 0, 0);
            #pragma unroll
            for (int r = 0; r < 4; ++r) {
                float v = (zza[j][r] + ee_l) - a[r];     // = d/2 (R2-exact order)
                unsigned int u = __builtin_bit_cast(unsigned int, v);
                bool tk = u < Bb[j][r];
                Bb[j][r] = tk ? u : Bb[j][r];
                Kk[j][r] = tk ? kge : Kk[j][r];
            }
        }
    }

    // ---- cross-lane reduce within 16-lane col groups, tie -> lowest k ----
    #pragma unroll
    for (int j = 0; j < 4; ++j) {
        const int rtg = rtbase + j;
        #pragma unroll
        for (int r = 0; r < 4; ++r) {
            unsigned int b0 = Bb[j][r]; int k0 = Kk[j][r];
            #pragma unroll
            for (int m = 1; m < 16; m <<= 1) {
                unsigned int ob = __shfl_xor((int)b0, m, 16); int ok = __shfl_xor(k0, m, 16);
                bool tk = (ob < b0) || (ob == b0 && ok < k0);
                b0 = tk ? ob : b0; k0 = tk ? ok : k0;
            }
            if (lr == 0) out[O_IDX + rtg * 16 + g * 4 + r] = (float)k0;
        }
    }
}

// ---------------- S: gather z_q + commitment + hist + PSUM panels -----------
__global__ __launch_bounds__(1024) void vq_scatter(
    const float* __restrict__ z, const float* __restrict__ emb,
    float* __restrict__ out, float* __restrict__ ws)
{
    __shared__ float smem[34816];   // [1024][33] sums + counts at 33792
    __shared__ float red[16];
    const int t = threadIdx.x;
    const int b = blockIdx.x;
    {
        float4 zero4 = {0.f, 0.f, 0.f, 0.f};
        float4* s4 = (float4*)smem;
        #pragma unroll
        for (int i = 0; i < 9; ++i) { int j = t + i * 1024; if (j < 8704) s4[j] = zero4; }
    }
    __syncthreads();

    const int row = b * 1024 + t;
    const int kk = (int)out[O_IDX + row];
    const float4* zg = (const float4*)(z + (size_t)row * DIM);
    const float4* eg = (const float4*)(emb + (size_t)kk * DIM);
    float4* og = (float4*)(out + O_ZQ + (size_t)row * DIM);
    float zv[32];
    float csum = 0.f;
    #pragma unroll
    for (int q = 0; q < 8; ++q) {
        float4 v = zg[q];
        float4 e = eg[q];
        zv[4*q] = v.x; zv[4*q+1] = v.y; zv[4*q+2] = v.z; zv[4*q+3] = v.w;
        float d0 = v.x - e.x, d1 = v.y - e.y, d2 = v.z - e.z, d3 = v.w - e.w;
        csum = fmaf(d0, d0, csum); csum = fmaf(d1, d1, csum);
        csum = fmaf(d2, d2, csum); csum = fmaf(d3, d3, csum);
        float4 o;
        o.x = v.x + (e.x - v.x); o.y = v.y + (e.y - v.y);
        o.z = v.z + (e.z - v.z); o.w = v.w + (e.w - v.w);
        og[q] = o;
    }
    atomicAdd(&smem[33792 + kk], 1.0f);
    #pragma unroll
    for (int i = 0; i < 32; ++i) atomicAdd(&smem[kk * 33 + i], zv[i]);

    #pragma unroll
    for (int off = 32; off > 0; off >>= 1) csum += __shfl_down(csum, off, 64);
    if ((t & 63) == 0) red[t >> 6] = csum;
    __syncthreads();

    // counts: global atomic adds of integer-valued floats (exact, deterministic)
    float cpart = smem[33792 + t];
    if (cpart != 0.f) atomicAdd(&ws[W_PCNT + t], cpart);

    float4* p4 = (float4*)(ws + W_PSUM + (size_t)b * (KCODES * DIM));
    #pragma unroll
    for (int c = 0; c < 8; ++c) {
        int j = t + c * 1024;
        int kr = j >> 3, e0 = (j & 7) * 4;
        float4 v;
        v.x = smem[kr * 33 + e0 + 0]; v.y = smem[kr * 33 + e0 + 1];
        v.z = smem[kr * 33 + e0 + 2]; v.w = smem[kr * 33 + e0 + 3];
        p4[j] = v;
    }
    if (t == 0) {
        float s = 0.f;
        #pragma unroll
        for (int i = 0; i < 16; ++i) s += red[i];
        ws[W_PCOM + b] = s;
    }
}

__global__ __launch_bounds__(1024) void vq_epilogue0(
    const float* __restrict__ cs_in, const float* __restrict__ ws,
    float* __restrict__ out, float* __restrict__ wsw)
{
    __shared__ float s1[1024], s2[1024];
    const int k = threadIdx.x;
    float c = ws[W_PCNT + k];
    float csn = 0.99f * cs_in[k] + 0.01f * c;
    out[O_CS + k] = csn;
    s1[k] = csn;
    s2[k] = (c == 0.f) ? 1.f : 0.f;
    __syncthreads();
    for (int s = 512; s > 0; s >>= 1) {
        if (k < s) { s1[k] += s1[k + s]; s2[k] += s2[k + s]; }
        __syncthreads();
    }
    float n = s1[0];
    float unused = s2[0];
    wsw[W_NORM + k] = n * (csn + 1e-5f) / (n + 1024.f * 1e-5f);
    __syncthreads();
    s1[k] = (k < 256) ? ws[W_PCOM + k] : 0.f;
    __syncthreads();
    for (int s = 512; s > 0; s >>= 1) {
        if (k < s) s1[k] += s1[k + s];
        __syncthreads();
    }
    if (k == 0) {
        out[O_CB] = 0.f;
        out[O_CL] = s1[0] / 8388608.f;
        out[O_UN] = unused;
    }
}

// ---------------- E1: PSUM reduction, 8-way split per element + LDS merge ----
// 256 blocks x 1024 threads: 8 threads per output element, each sums 32 of
// the 256 partials (8 loads in flight), then fixed-order pairwise combine.
__global__ __launch_bounds__(1024) void vq_epilogue1(
    const float* __restrict__ ea, const float* __restrict__ ws,
    float* __restrict__ out)
{
    __shared__ float part[8][128];
    const int t = threadIdx.x;
    const int e = t & 127;
    const int seg = t >> 7;                    // 0..7
    const int id = blockIdx.x * 128 + e;       // < 32768
    float s = 0.f;
    #pragma unroll 8
    for (int bb = seg * 32; bb < seg * 32 + 32; ++bb)
        s += ws[W_PSUM + (size_t)bb * (KCODES * DIM) + id];
    part[seg][e] = s;
    __syncthreads();
    if (seg == 0) {
        float es = ((part[0][e] + part[1][e]) + (part[2][e] + part[3][e]))
                 + ((part[4][e] + part[5][e]) + (part[6][e] + part[7][e]));
        float ean = 0.99f * ea[id] + 0.01f * es;
        out[O_EA + id] = ean;
        out[O_EMB + id] = ean / ws[W_NORM + (id >> 5)];
    }
}

extern "C" void kernel_launch(void* const* d_in, const int* in_sizes, int n_in,
                              void* d_out, int out_size, void* d_ws, size_t ws_size,
                              hipStream_t stream)
{
    const float* z   = (const float*)d_in[0];
    const float* emb = (const float*)d_in[1];
    const float* ea  = (const float*)d_in[2];
    const float* cs  = (const float*)d_in[3];
    float* out = (float*)d_out;
    float* ws  = (float*)d_ws;

    hipMemsetAsync(ws + W_PCNT, 0, KCODES * sizeof(float), stream);
    vq_prep_z<<<1024, 256, 0, stream>>>(z, ws);
    vq_prep_e<<<4, 256, 0, stream>>>(emb, ws);
    vq_argmin_mfma<<<1024, 256, 0, stream>>>(z, ws, out);
    vq_scatter<<<256, 1024, 0, stream>>>(z, emb, out, ws);
    vq_epilogue0<<<1, 1024, 0, stream>>>(cs, ws, out, ws);
    vq_epilogue1<<<256, 1024, 0, stream>>>(ea, ws, out);
}

// Round 13
// 165.019 us; speedup vs baseline: 1.9304x; 1.0535x over previous
//
#include <hip/hip_runtime.h>
#include <hip/hip_bf16.h>
#include <float.h>

#define DIM 32
#define KCODES 1024
#define NROWS 262144

// output offsets (floats, reference return order)
#define O_ZQ   0
#define O_CB   8388608
#define O_CL   8388609
#define O_IDX  8388610
#define O_UN   8650754
#define O_EMB  8650755
#define O_CS   8683523
#define O_EA   8684547

// workspace layout (float offsets)
#define W_PCNT 0          // counts[1024] via global atomics (zeroed in vq_prep)
#define W_PSUM 262144     // [256][1024*32] scatter partials (32MB)
#define W_PCOM 8650752    // [256] commitment partials (scatter blocks)
#define W_ZZH  8652032    // [262144] zz/2
#define W_EEH  8914176    // [1024] ee/2
#define W_BF   8915200    // ushort region: 64 kt x 3 splits x 64 lanes x 8 bf16 (192KB)

typedef __attribute__((ext_vector_type(8))) short bf16x8;
typedef __attribute__((ext_vector_type(4))) float f32x4;

#define MFMA16 __builtin_amdgcn_mfma_f32_16x16x32_bf16

static __device__ __forceinline__ unsigned short f2bf(float x) {
    __hip_bfloat16 h = __float2bfloat16(x);           // RNE
    return __builtin_bit_cast(unsigned short, h);
}
static __device__ __forceinline__ float bf2f(unsigned short u) {
    unsigned int v = ((unsigned int)u) << 16;
    return __builtin_bit_cast(float, v);
}
static __device__ __forceinline__ float pw8_sq(const float* x) {
    float w[32];
    #pragma unroll
    for (int i = 0; i < 32; ++i) w[i] = __fmul_rn(x[i], x[i]);
    float r[8];
    #pragma unroll
    for (int j = 0; j < 8; ++j) r[j] = ((w[j] + w[8 + j]) + w[16 + j]) + w[24 + j];
    return ((r[0] + r[1]) + (r[2] + r[3])) + ((r[4] + r[5]) + (r[6] + r[7]));
}

// ---------------- P: fused prep (blocks 0..1023: zz/2; 1024..1027: codebook) --
__global__ __launch_bounds__(256) void vq_prep(
    const float* __restrict__ z, const float* __restrict__ emb,
    float* __restrict__ ws)
{
    const int t = threadIdx.x;
    const int b = blockIdx.x;
    if (b < 1024) {
        int row = b * 256 + t;
        float x[32];
        const float4* zg = (const float4*)(z + (size_t)row * DIM);
        #pragma unroll
        for (int q = 0; q < 8; ++q) {
            float4 v = zg[q];
            x[4*q] = v.x; x[4*q+1] = v.y; x[4*q+2] = v.z; x[4*q+3] = v.w;
        }
        ws[W_ZZH + row] = 0.5f * pw8_sq(x);
        return;
    }
    int c = (b - 1024) * 256 + t;
    ws[W_PCNT + c] = 0.f;                 // zero counts (replaces memset launch)
    float x[32];
    const float4* eg = (const float4*)(emb + (size_t)c * DIM);
    #pragma unroll
    for (int q = 0; q < 8; ++q) {
        float4 v = eg[q];
        x[4*q] = v.x; x[4*q+1] = v.y; x[4*q+2] = v.z; x[4*q+3] = v.w;
    }
    ws[W_EEH + c] = 0.5f * pw8_sq(x);

    unsigned short hb[3][32];
    #pragma unroll
    for (int i = 0; i < 32; ++i) {
        float v = x[i];
        unsigned short h0 = f2bf(v); float f0 = bf2f(h0); float r1 = v - f0;
        unsigned short h1 = f2bf(r1); float f1 = bf2f(h1); float r2 = r1 - f1;
        unsigned short h2 = f2bf(r2);   // exact: v = h0+h1+h2
        hb[0][i] = h0; hb[1][i] = h1; hb[2][i] = h2;
    }
    // B-frag: lane l holds B[k=(l>>4)*8+e][col=l&15]; frag index (kt*3+s)*64+lane
    bf16x8* bf = (bf16x8*)(ws + W_BF);
    int kt = c >> 4, cl = c & 15;
    #pragma unroll
    for (int s = 0; s < 3; ++s) {
        #pragma unroll
        for (int j = 0; j < 4; ++j) {
            bf16x8 pk;
            #pragma unroll
            for (int e = 0; e < 8; ++e) pk[e] = (short)hb[s][j*8 + e];
            bf[(kt*3 + s)*64 + j*16 + cl] = pk;
        }
    }
}

// ---------------- A: MFMA distance argmin -> indices (R5 proven, 100.6us) ---
// 1024 blocks x 256 threads (4 waves), j=4 row-tiles/wave, B-frags stream
// from L2 (no LDS staging, no k-loop barriers). kt unroll 2 — do NOT deepen
// (unroll 4 remats z loads in-loop: 581MB HBM, R10). New: shared zero C-quad.
__global__ __launch_bounds__(256, 4) void vq_argmin_mfma(
    const float* __restrict__ z, const float* __restrict__ wsc,
    float* __restrict__ out)
{
    __shared__ float eesh[1024];
    const int t = threadIdx.x;
    const int lane = t & 63, w = t >> 6;
    const int g = lane >> 4, lr = lane & 15;

    const bf16x8* bvG = (const bf16x8*)(wsc + W_BF);

    #pragma unroll
    for (int i = 0; i < 4; ++i) eesh[t + i * 256] = wsc[W_EEH + t + i * 256];

    // ---- load 4 z row-tiles: split to bf16x3 A-frags + zz ----
    const int rtbase = blockIdx.x * 16 + w * 4;
    bf16x8 zh[4], zm[4], zl[4];
    float zza[4][4];
    #pragma unroll
    for (int j = 0; j < 4; ++j) {
        const int rtg = rtbase + j;
        const float* zp = z + ((size_t)(rtg * 16 + lr)) * DIM + g * 8;
        float4 a4 = *(const float4*)zp, b4 = *(const float4*)(zp + 4);
        float xs[8] = {a4.x, a4.y, a4.z, a4.w, b4.x, b4.y, b4.z, b4.w};
        #pragma unroll
        for (int e = 0; e < 8; ++e) {
            float v = xs[e];
            unsigned short h0 = f2bf(v); float f0 = bf2f(h0); float r1 = v - f0;
            unsigned short h1 = f2bf(r1); float f1 = bf2f(h1); float r2 = r1 - f1;
            zh[j][e] = (short)h0; zm[j][e] = (short)h1; zl[j][e] = (short)f2bf(r2);
        }
        float4 zv = *(const float4*)(wsc + W_ZZH + rtg * 16 + g * 4);
        zza[j][0] = zv.x; zza[j][1] = zv.y; zza[j][2] = zv.z; zza[j][3] = zv.w;
    }

    unsigned int Bb[4][4]; int Kk[4][4];
    #pragma unroll
    for (int j = 0; j < 4; ++j)
        #pragma unroll
        for (int r = 0; r < 4; ++r) { Bb[j][r] = 0xFFFFFFFFu; Kk[j][r] = 0; }

    __syncthreads();   // eesh ready

    const f32x4 ZQ = {0.f, 0.f, 0.f, 0.f};   // shared C-init quad (no per-kt movs)

    #pragma unroll 2
    for (int kt = 0; kt < 64; ++kt) {
        bf16x8 eh = bvG[(kt * 3 + 0) * 64 + lane];
        bf16x8 em = bvG[(kt * 3 + 1) * 64 + lane];
        bf16x8 el = bvG[(kt * 3 + 2) * 64 + lane];
        float ee_l = eesh[kt * 16 + lr];
        int kge = kt * 16 + lr;
        #pragma unroll
        for (int j = 0; j < 4; ++j) {
            f32x4 a = MFMA16(zh[j], eh, ZQ, 0, 0, 0);   // C = 0 exactly, as before
            a = MFMA16(zh[j], em, a, 0, 0, 0);
            a = MFMA16(zm[j], eh, a, 0, 0, 0);
            a = MFMA16(zh[j], el, a, 0, 0, 0);
            a = MFMA16(zl[j], eh, a, 0, 0, 0);
            a = MFMA16(zm[j], em, a, 0, 0, 0);
            #pragma unroll
            for (int r = 0; r < 4; ++r) {
                float v = (zza[j][r] + ee_l) - a[r];     // = d/2 (R2-exact order)
                unsigned int u = __builtin_bit_cast(unsigned int, v);
                bool tk = u < Bb[j][r];
                Bb[j][r] = tk ? u : Bb[j][r];
                Kk[j][r] = tk ? kge : Kk[j][r];
            }
        }
    }

    // ---- cross-lane reduce within 16-lane col groups, tie -> lowest k ----
    #pragma unroll
    for (int j = 0; j < 4; ++j) {
        const int rtg = rtbase + j;
        #pragma unroll
        for (int r = 0; r < 4; ++r) {
            unsigned int b0 = Bb[j][r]; int k0 = Kk[j][r];
            #pragma unroll
            for (int m = 1; m < 16; m <<= 1) {
                unsigned int ob = __shfl_xor((int)b0, m, 16); int ok = __shfl_xor(k0, m, 16);
                bool tk = (ob < b0) || (ob == b0 && ok < k0);
                b0 = tk ? ob : b0; k0 = tk ? ok : k0;
            }
            if (lr == 0) out[O_IDX + rtg * 16 + g * 4 + r] = (float)k0;
        }
    }
}

// ---------------- S: gather z_q + commitment + hist + PSUM panels -----------
__global__ __launch_bounds__(1024) void vq_scatter(
    const float* __restrict__ z, const float* __restrict__ emb,
    float* __restrict__ out, float* __restrict__ ws)
{
    __shared__ float smem[34816];   // [1024][33] sums + counts at 33792
    __shared__ float red[16];
    const int t = threadIdx.x;
    const int b = blockIdx.x;
    {
        float4 zero4 = {0.f, 0.f, 0.f, 0.f};
        float4* s4 = (float4*)smem;
        #pragma unroll
        for (int i = 0; i < 9; ++i) { int j = t + i * 1024; if (j < 8704) s4[j] = zero4; }
    }
    __syncthreads();

    const int row = b * 1024 + t;
    const int kk = (int)out[O_IDX + row];
    const float4* zg = (const float4*)(z + (size_t)row * DIM);
    const float4* eg = (const float4*)(emb + (size_t)kk * DIM);
    float4* og = (float4*)(out + O_ZQ + (size_t)row * DIM);
    float zv[32];
    float csum = 0.f;
    #pragma unroll
    for (int q = 0; q < 8; ++q) {
        float4 v = zg[q];
        float4 e = eg[q];
        zv[4*q] = v.x; zv[4*q+1] = v.y; zv[4*q+2] = v.z; zv[4*q+3] = v.w;
        float d0 = v.x - e.x, d1 = v.y - e.y, d2 = v.z - e.z, d3 = v.w - e.w;
        csum = fmaf(d0, d0, csum); csum = fmaf(d1, d1, csum);
        csum = fmaf(d2, d2, csum); csum = fmaf(d3, d3, csum);
        float4 o;
        o.x = v.x + (e.x - v.x); o.y = v.y + (e.y - v.y);
        o.z = v.z + (e.z - v.z); o.w = v.w + (e.w - v.w);
        og[q] = o;
    }
    atomicAdd(&smem[33792 + kk], 1.0f);
    #pragma unroll
    for (int i = 0; i < 32; ++i) atomicAdd(&smem[kk * 33 + i], zv[i]);

    #pragma unroll
    for (int off = 32; off > 0; off >>= 1) csum += __shfl_down(csum, off, 64);
    if ((t & 63) == 0) red[t >> 6] = csum;
    __syncthreads();

    // counts: global atomic adds of integer-valued floats (exact, deterministic)
    float cpart = smem[33792 + t];
    if (cpart != 0.f) atomicAdd(&ws[W_PCNT + t], cpart);

    float4* p4 = (float4*)(ws + W_PSUM + (size_t)b * (KCODES * DIM));
    #pragma unroll
    for (int c = 0; c < 8; ++c) {
        int j = t + c * 1024;
        int kr = j >> 3, e0 = (j & 7) * 4;
        float4 v;
        v.x = smem[kr * 33 + e0 + 0]; v.y = smem[kr * 33 + e0 + 1];
        v.z = smem[kr * 33 + e0 + 2]; v.w = smem[kr * 33 + e0 + 3];
        p4[j] = v;
    }
    if (t == 0) {
        float s = 0.f;
        #pragma unroll
        for (int i = 0; i < 16; ++i) s += red[i];
        ws[W_PCOM + b] = s;
    }
}

// ---------------- E: fused epilogue (cs/norm/unused/loss + PSUM reduce) -----
// 256 blocks x 1024 threads. Every block redundantly (and deterministically)
// computes csn[1024], n, and norm from the global counts; block 0 additionally
// writes O_CS/O_CB/O_CL/O_UN. Then each block reduces its 128 PSUM elements.
__global__ __launch_bounds__(1024) void vq_epilogue(
    const float* __restrict__ cs_in, const float* __restrict__ ea,
    const float* __restrict__ ws, float* __restrict__ out)
{
    __shared__ float s1[1024], s2[1024], normsh[1024];
    __shared__ float part[8][128];
    const int t = threadIdx.x;
    const int b = blockIdx.x;

    float c = ws[W_PCNT + t];
    float csn = 0.99f * cs_in[t] + 0.01f * c;
    s1[t] = csn;
    s2[t] = (c == 0.f) ? 1.f : 0.f;
    __syncthreads();
    for (int s = 512; s > 0; s >>= 1) {
        if (t < s) { s1[t] += s1[t + s]; s2[t] += s2[t + s]; }
        __syncthreads();
    }
    float n = s1[0];
    float unused = s2[0];
    normsh[t] = n * (csn + 1e-5f) / (n + 1024.f * 1e-5f);
    __syncthreads();

    if (b == 0) {
        out[O_CS + t] = csn;
        s1[t] = (t < 256) ? ws[W_PCOM + t] : 0.f;
        __syncthreads();
        for (int s = 512; s > 0; s >>= 1) {
            if (t < s) s1[t] += s1[t + s];
            __syncthreads();
        }
        if (t == 0) {
            out[O_CB] = 0.f;
            out[O_CL] = s1[0] / 8388608.f;
            out[O_UN] = unused;
        }
    }

    // PSUM reduce: 8 threads per output element, each sums 32 of 256 partials
    const int e = t & 127;
    const int seg = t >> 7;                    // 0..7
    const int id = b * 128 + e;                // < 32768
    float s = 0.f;
    #pragma unroll 8
    for (int bb = seg * 32; bb < seg * 32 + 32; ++bb)
        s += ws[W_PSUM + (size_t)bb * (KCODES * DIM) + id];
    part[seg][e] = s;
    __syncthreads();
    if (seg == 0) {
        float es = ((part[0][e] + part[1][e]) + (part[2][e] + part[3][e]))
                 + ((part[4][e] + part[5][e]) + (part[6][e] + part[7][e]));
        float ean = 0.99f * ea[id] + 0.01f * es;
        out[O_EA + id] = ean;
        out[O_EMB + id] = ean / normsh[id >> 5];
    }
}

extern "C" void kernel_launch(void* const* d_in, const int* in_sizes, int n_in,
                              void* d_out, int out_size, void* d_ws, size_t ws_size,
                              hipStream_t stream)
{
    const float* z   = (const float*)d_in[0];
    const float* emb = (const float*)d_in[1];
    const float* ea  = (const float*)d_in[2];
    const float* cs  = (const float*)d_in[3];
    float* out = (float*)d_out;
    float* ws  = (float*)d_ws;

    vq_prep<<<1028, 256, 0, stream>>>(z, emb, ws);
    vq_argmin_mfma<<<1024, 256, 0, stream>>>(z, ws, out);
    vq_scatter<<<256, 1024, 0, stream>>>(z, emb, out, ws);
    vq_epilogue<<<256, 1024, 0, stream>>>(cs, ea, ws, out);
}